// Round 10
// baseline (209.374 us; speedup 1.0000x reference)
//
#include <hip/hip_runtime.h>
#include <stdint.h>
#include <type_traits>

#define DIN 1024
#define DIMM 1024
#define NH 16
#define HD 64
#define SEQ 2048
#define BATCH 2
#define MTOT (BATCH*SEQ)   // 4096
#define LDP 72             // attn P-tile leading dim (64 + 8)
#define SCALE 0.125f       // 1/sqrt(64)

typedef __bf16 bf16;
typedef __bf16 bf16x8 __attribute__((ext_vector_type(8)));
typedef __bf16 bf16x4 __attribute__((ext_vector_type(4)));
typedef float f32x4 __attribute__((ext_vector_type(4)));

// async global->LDS, 16B per lane (HW: wave-uniform LDS base + lane*16).
// Staged tiles use an XOR swizzle: LDS slot (row, c8) holds global col-group
// c8 ^ (row & 7); readers XOR their col-group by (row & 7). Spreads stride-64
// fragment reads across all 32 banks with zero padding.
__device__ __forceinline__ void async16(bf16* lds, const bf16* g) {
  __builtin_amdgcn_global_load_lds(
      (const __attribute__((address_space(1))) void*)g,
      (__attribute__((address_space(3))) void*)lds, 16, 0, 0);
}

// Load 8 contiguous elements as bf16x8, converting from fp32 if needed.
template<typename T>
__device__ __forceinline__ bf16x8 ld8bf16(const T* __restrict__ p) {
  if constexpr (std::is_same<T, float>::value) {
    const f32x4* q = (const f32x4*)p;
    f32x4 a = q[0], b = q[1];
    bf16x8 r;
    r[0] = (bf16)a[0]; r[1] = (bf16)a[1]; r[2] = (bf16)a[2]; r[3] = (bf16)a[3];
    r[4] = (bf16)b[0]; r[5] = (bf16)b[1]; r[6] = (bf16)b[2]; r[7] = (bf16)b[3];
    return r;
  } else {
    return *(const bf16x8*)p;
  }
}

// ---------------- QKV fused GEMM, fp32 inputs converted in-staging ---------
// C = x * W^T, tile 128x128, BK=64. W selected per N-block (block-uniform).
// n<1024 -> Q, <2048 -> K, else V written TRANSPOSED into Vt.
__global__ __launch_bounds__(256) void qkv_gemm(const float* __restrict__ x,
                                                const float* __restrict__ wq,
                                                const float* __restrict__ wk,
                                                const float* __restrict__ wv,
                                                bf16* __restrict__ Q,
                                                bf16* __restrict__ Kb,
                                                bf16* __restrict__ Vt) {
  __shared__ bf16 As[128 * 64];
  __shared__ bf16 Bs[128 * 64];
  const int tid  = threadIdx.x;
  const int lane = tid & 63;
  const int wave = tid >> 6;
  const int lrow = lane & 15;
  const int quad = lane >> 4;
  const int wr = (wave >> 1) * 64;
  const int wc = (wave & 1) * 64;
  const int mbase = blockIdx.y * 128;
  const int nbase = blockIdx.x * 128;
  const int srow = tid >> 3;
  const int scol = (tid & 7) * 8;
  const int sx   = ((tid & 7) ^ (srow & 7)) * 8;

  // block-uniform weight select (128-row N-tiles never straddle a weight)
  const float* W = (nbase < 1024) ? wq : (nbase < 2048) ? wk : wv;
  const int nb2  = nbase & 1023;

  f32x4 acc[4][4] = {};

  for (int k0 = 0; k0 < DIN; k0 += 64) {
#pragma unroll
    for (int i = 0; i < 4; ++i) {
      *(bf16x8*)&As[(i * 32 + srow) * 64 + scol] =
          ld8bf16(&x[(size_t)(mbase + i * 32 + srow) * DIN + k0 + sx]);
      *(bf16x8*)&Bs[(i * 32 + srow) * 64 + scol] =
          ld8bf16(&W[(size_t)(nb2 + i * 32 + srow) * DIN + k0 + sx]);
    }
    __syncthreads();
#pragma unroll
    for (int h = 0; h < 2; ++h) {
      const int cx = ((h * 4 + quad) ^ (lrow & 7)) * 8;
      bf16x8 af[4], bfr[4];
#pragma unroll
      for (int i = 0; i < 4; ++i) {
        af[i]  = *(const bf16x8*)&As[(wr + i * 16 + lrow) * 64 + cx];
        bfr[i] = *(const bf16x8*)&Bs[(wc + i * 16 + lrow) * 64 + cx];
      }
#pragma unroll
      for (int mt = 0; mt < 4; ++mt)
#pragma unroll
        for (int nt = 0; nt < 4; ++nt)
          acc[mt][nt] = __builtin_amdgcn_mfma_f32_16x16x32_bf16(af[mt], bfr[nt], acc[mt][nt], 0, 0, 0);
    }
    __syncthreads();
  }

#pragma unroll
  for (int mt = 0; mt < 4; ++mt) {
    const int m0 = mbase + wr + mt * 16 + quad * 4;
#pragma unroll
    for (int nt = 0; nt < 4; ++nt) {
      const int n16 = nbase + wc + nt * 16;   // region uniform per 16-col tile
      const int n = n16 + lrow;
      if (n16 < 1024) {
#pragma unroll
        for (int rr = 0; rr < 4; ++rr)
          Q[(size_t)(m0 + rr) * 1024 + n] = (bf16)acc[mt][nt][rr];
      } else if (n16 < 2048) {
#pragma unroll
        for (int rr = 0; rr < 4; ++rr)
          Kb[(size_t)(m0 + rr) * 1024 + (n - 1024)] = (bf16)acc[mt][nt][rr];
      } else {
        const int nn = n - 2048;
        const int row = ((m0 >> 11) * 16 + (nn >> 6)) * 64 + (nn & 63);
        bf16x4 ov;
#pragma unroll
        for (int rr = 0; rr < 4; ++rr) ov[rr] = (bf16)acc[mt][nt][rr];
        *(bf16x4*)&Vt[(size_t)row * SEQ + (m0 & 2047)] = ov;
      }
    }
  }
}

// ---------------- proj GEMM: tile 128x64 (2 blocks/CU), wo fp32 in-staging --
__global__ __launch_bounds__(256) void proj_gemm(const bf16* __restrict__ A,
                                                 const float* __restrict__ W,
                                                 float* __restrict__ C) {
  __shared__ bf16 As[128 * 64];
  __shared__ bf16 Bs[64 * 64];
  const int tid  = threadIdx.x;
  const int lane = tid & 63;
  const int wave = tid >> 6;
  const int lrow = lane & 15;
  const int quad = lane >> 4;
  const int wr = (wave >> 1) * 64;
  const int wc = (wave & 1) * 32;
  const int mbase = blockIdx.y * 128;
  const int nbase = blockIdx.x * 64;
  const int srow = tid >> 3;
  const int scol = (tid & 7) * 8;
  const int sx   = ((tid & 7) ^ (srow & 7)) * 8;

  f32x4 acc[4][2] = {};

  for (int k0 = 0; k0 < DIMM; k0 += 64) {
#pragma unroll
    for (int i = 0; i < 4; ++i)
      async16(&As[(i * 32 + srow) * 64 + scol],
              &A[(size_t)(mbase + i * 32 + srow) * DIMM + k0 + sx]);
#pragma unroll
    for (int i = 0; i < 2; ++i)
      *(bf16x8*)&Bs[(i * 32 + srow) * 64 + scol] =
          ld8bf16(&W[(size_t)(nbase + i * 32 + srow) * DIMM + k0 + sx]);
    __syncthreads();
#pragma unroll
    for (int h = 0; h < 2; ++h) {
      const int cx = ((h * 4 + quad) ^ (lrow & 7)) * 8;
      bf16x8 af[4], bfr[2];
#pragma unroll
      for (int i = 0; i < 4; ++i)
        af[i] = *(const bf16x8*)&As[(wr + i * 16 + lrow) * 64 + cx];
#pragma unroll
      for (int i = 0; i < 2; ++i)
        bfr[i] = *(const bf16x8*)&Bs[(wc + i * 16 + lrow) * 64 + cx];
#pragma unroll
      for (int mt = 0; mt < 4; ++mt)
#pragma unroll
        for (int nt = 0; nt < 2; ++nt)
          acc[mt][nt] = __builtin_amdgcn_mfma_f32_16x16x32_bf16(af[mt], bfr[nt], acc[mt][nt], 0, 0, 0);
    }
    __syncthreads();
  }

#pragma unroll
  for (int mt = 0; mt < 4; ++mt) {
    const int m0 = mbase + wr + mt * 16 + quad * 4;
#pragma unroll
    for (int nt = 0; nt < 2; ++nt) {
      const int n = nbase + wc + nt * 16 + lrow;
#pragma unroll
      for (int rr = 0; rr < 4; ++rr)
        C[(size_t)(m0 + rr) * 1024 + n] = acc[mt][nt][rr];
    }
  }
}

// ---------------- Causal flash attention, 64-row blocks (4 waves) ----------
// Block = 256 thr = 64 q-rows of one (b,h). K/Vt staged to double-buffered
// XOR-swizzled LDS via global_load_lds; conflict-free ds_read_b128 inner loop.
__global__ __launch_bounds__(256, 4) void attn(const bf16* __restrict__ Q,
                                               const bf16* __restrict__ K,
                                               const bf16* __restrict__ Vt,
                                               bf16* __restrict__ O) {
  __shared__ bf16 Ks[2][64 * 64];
  __shared__ bf16 Vts[2][64 * 64];
  __shared__ bf16 Plds[4][16 * LDP];
  const int tid  = threadIdx.x;
  const int wave = tid >> 6;
  const int lane = tid & 63;
  const int lrow = lane & 15;
  const int quad = lane >> 4;
  const int bh = blockIdx.x & 31;        // same-bh -> same XCD residue
  // balanced qc partition: each mod-8 class {g0,15-g0,16+g0,31-g0} sums 66
  const int g  = blockIdx.x >> 5;        // 0..31
  const int j  = g >> 3, g0 = g & 7;
  const int qc = (j == 0) ? g0 : (j == 1) ? 15 - g0 : (j == 2) ? 16 + g0 : 31 - g0;
  const int b  = bh >> 4;
  const int h  = bh & 15;
  const int qw = qc * 64 + wave * 16;    // this wave's q-tile base
  const int ntiles = qc + 1;

  const bf16* Qh  = Q  + (size_t)(b * SEQ) * DIMM + h * HD;
  const bf16* Kh  = K  + (size_t)(b * SEQ) * DIMM + h * HD;
  const bf16* Vth = Vt + (size_t)bh * 64 * SEQ;
  bf16* Pw = Plds[wave];

  // staging coords: 256 thr cover 32 rows x 128B per async group
  const int srow = tid >> 3;             // 0..31
  const int scol = (tid & 7) * 8;
  const int sx   = ((tid & 7) ^ (srow & 7)) * 8;
  const int cx0 = ((0 + quad) ^ (lrow & 7)) * 8;
  const int cx1 = ((4 + quad) ^ (lrow & 7)) * 8;

  bf16x8 qf0 = *(const bf16x8*)&Qh[(size_t)(qw + lrow) * DIMM + quad * 8];
  bf16x8 qf1 = *(const bf16x8*)&Qh[(size_t)(qw + lrow) * DIMM + 32 + quad * 8];

  // prologue: stage tile 0 into buf 0
#pragma unroll
  for (int i = 0; i < 2; ++i) {
    async16(&Ks[0][(i * 32 + srow) * 64 + scol],  &Kh[(size_t)(i * 32 + srow) * DIMM + sx]);
    async16(&Vts[0][(i * 32 + srow) * 64 + scol], &Vth[(size_t)(i * 32 + srow) * SEQ + sx]);
  }
  __syncthreads();

  float m_i = -1e30f, l_i = 0.f;
  f32x4 o_acc[4] = {};
  int cur = 0;

  for (int kt = 0; kt < ntiles; ++kt) {
    const int kbase = kt * 64;
    // issue next tile's staging into the other buffer (completes at barrier)
    if (kt + 1 < ntiles) {
      const int nb = kbase + 64;
#pragma unroll
      for (int i = 0; i < 2; ++i) {
        async16(&Ks[cur ^ 1][(i * 32 + srow) * 64 + scol],
                &Kh[(size_t)(nb + i * 32 + srow) * DIMM + sx]);
        async16(&Vts[cur ^ 1][(i * 32 + srow) * 64 + scol],
                &Vth[(size_t)(i * 32 + srow) * SEQ + nb + sx]);
      }
    }
    const bf16* Kc = Ks[cur];
    const bf16* Vc = Vts[cur];
    // ---- S^T = K Q^T from LDS ----
    f32x4 s[4] = {};
#pragma unroll
    for (int gg = 0; gg < 4; ++gg) {
      bf16x8 kf0 = *(const bf16x8*)&Kc[(gg * 16 + lrow) * 64 + cx0];
      bf16x8 kf1 = *(const bf16x8*)&Kc[(gg * 16 + lrow) * 64 + cx1];
      s[gg] = __builtin_amdgcn_mfma_f32_16x16x32_bf16(kf0, qf0, s[gg], 0, 0, 0);
      s[gg] = __builtin_amdgcn_mfma_f32_16x16x32_bf16(kf1, qf1, s[gg], 0, 0, 0);
    }
    // ---- causal mask: boundary tile only ----
    if (kt == ntiles - 1) {
      const int qrow = qw + lrow;
#pragma unroll
      for (int gg = 0; gg < 4; ++gg)
#pragma unroll
        for (int r = 0; r < 4; ++r)
          s[gg][r] = (kbase + gg * 16 + quad * 4 + r > qrow) ? -1e30f : s[gg][r];
    }
    // ---- online softmax over k: in-lane + 2 shfl ----
    float pm = s[0][0];
#pragma unroll
    for (int gg = 0; gg < 4; ++gg)
#pragma unroll
      for (int r = 0; r < 4; ++r) pm = fmaxf(pm, s[gg][r]);
    pm = fmaxf(pm, __shfl_xor(pm, 16));
    pm = fmaxf(pm, __shfl_xor(pm, 32));
    const float mn = fmaxf(m_i, pm);
    const float al = __expf((m_i - mn) * SCALE);
    float sum = 0.f;
#pragma unroll
    for (int gg = 0; gg < 4; ++gg) {
      bf16x4 pk;
#pragma unroll
      for (int r = 0; r < 4; ++r) {
        const float p = __expf((s[gg][r] - mn) * SCALE);
        sum += p;
        pk[r] = (bf16)p;
      }
      *(bf16x4*)&Pw[lrow * LDP + gg * 16 + quad * 4] = pk;
    }
    sum += __shfl_xor(sum, 16);
    sum += __shfl_xor(sum, 32);
    l_i = l_i * al + sum;
    m_i = mn;
#pragma unroll
    for (int dt = 0; dt < 4; ++dt)
#pragma unroll
      for (int r = 0; r < 4; ++r)
        o_acc[dt][r] *= al;
    // ---- vf loads between P write and read (covers LDS turnaround) ----
    bf16x8 vf[8];
#pragma unroll
    for (int dt = 0; dt < 4; ++dt) {
      vf[2 * dt]     = *(const bf16x8*)&Vc[(dt * 16 + lrow) * 64 + cx0];
      vf[2 * dt + 1] = *(const bf16x8*)&Vc[(dt * 16 + lrow) * 64 + cx1];
    }
    bf16x8 pf0 = *(const bf16x8*)&Pw[lrow * LDP + quad * 8];
    bf16x8 pf1 = *(const bf16x8*)&Pw[lrow * LDP + 32 + quad * 8];
    // ---- O^T += Vt P^T ----
#pragma unroll
    for (int dt = 0; dt < 4; ++dt) {
      o_acc[dt] = __builtin_amdgcn_mfma_f32_16x16x32_bf16(vf[2 * dt],     pf0, o_acc[dt], 0, 0, 0);
      o_acc[dt] = __builtin_amdgcn_mfma_f32_16x16x32_bf16(vf[2 * dt + 1], pf1, o_acc[dt], 0, 0, 0);
    }
    __syncthreads();   // drains async staging; protects buffer swap
    cur ^= 1;
  }

  // ---- epilogue ----
  const float rl = __builtin_amdgcn_rcpf(l_i);
  bf16* Ob = O + (size_t)(b * SEQ + qw + lrow) * DIMM + h * HD;
#pragma unroll
  for (int dt = 0; dt < 4; ++dt) {
    bf16x4 ov;
#pragma unroll
    for (int r = 0; r < 4; ++r)
      ov[r] = (bf16)(o_acc[dt][r] * rl);
    *(bf16x4*)&Ob[dt * 16 + quad * 4] = ov;
  }
}

// ---------------- launch ----------------
extern "C" void kernel_launch(void* const* d_in, const int* in_sizes, int n_in,
                              void* d_out, int out_size, void* d_ws, size_t ws_size,
                              hipStream_t stream) {
  const float* x  = (const float*)d_in[0];
  const float* wq = (const float*)d_in[1];
  const float* wk = (const float*)d_in[2];
  const float* wv = (const float*)d_in[3];
  const float* wo = (const float*)d_in[4];

  const size_t M4 = (size_t)MTOT * DIMM;  // 4M elems
  bf16* Q   = (bf16*)d_ws;                // 4M
  bf16* Kb  = Q + M4;                     // 4M
  bf16* Vt  = Kb + M4;                    // 4M
  bf16* CTX = Vt + M4;                    // 4M
  float* out = (float*)d_out;

  qkv_gemm<<<dim3(3072 / 128, MTOT / 128), dim3(256), 0, stream>>>(x, wq, wk, wv, Q, Kb, Vt);
  attn<<<dim3(BATCH * NH * (SEQ / 64)), dim3(256), 0, stream>>>(Q, Kb, Vt, CTX);
  proj_gemm<<<dim3(1024 / 64, MTOT / 128), dim3(256), 0, stream>>>(CTX, wo, out);
}

// Round 11
// 187.516 us; speedup vs baseline: 1.1166x; 1.1166x over previous
//
#include <hip/hip_runtime.h>
#include <stdint.h>

#define DIN 1024
#define DIMM 1024
#define NH 16
#define HD 64
#define SEQ 2048
#define BATCH 2
#define MTOT (BATCH*SEQ)   // 4096
#define LDP 72             // attn P-tile leading dim (64 + 8)
#define SCALE 0.125f       // 1/sqrt(64)

typedef __bf16 bf16;
typedef __bf16 bf16x8 __attribute__((ext_vector_type(8)));
typedef __bf16 bf16x4 __attribute__((ext_vector_type(4)));
typedef float f32x4 __attribute__((ext_vector_type(4)));

// async global->LDS, 16B per lane (HW: wave-uniform LDS base + lane*16).
// Staged tiles use an XOR swizzle: LDS slot (row, c8) holds global col-group
// c8 ^ (row & 7); readers XOR their col-group by (row & 7). Spreads stride-64
// fragment reads across all 32 banks with zero padding.
__device__ __forceinline__ void async16(bf16* lds, const bf16* g) {
  __builtin_amdgcn_global_load_lds(
      (const __attribute__((address_space(1))) void*)g,
      (__attribute__((address_space(3))) void*)lds, 16, 0, 0);
}

// ---------------- fp32 -> bf16 convert: x (4M) + wq|wk|wv|wo (4M) ----------
// Pre-converting is a COMPRESSION pass: GEMMs re-read their inputs ~3x across
// XCDs, so bf16 halves all downstream HBM traffic (R10 fp32-direct: 80 MB
// qkv fetch, net regression).
__global__ __launch_bounds__(256) void convert_all(const float* __restrict__ x,
                                                   const float* __restrict__ wq,
                                                   const float* __restrict__ wk,
                                                   const float* __restrict__ wv,
                                                   const float* __restrict__ wo,
                                                   bf16* __restrict__ xb,
                                                   bf16* __restrict__ Wb) {
  const int t = blockIdx.x * 256 + threadIdx.x;
#pragma unroll
  for (int i = 0; i < 4; ++i) {
    const int c = t + i * 262144;   // 8-elem chunk id, total 1048576
    const float* src;
    bf16* dst;
    if (c < 524288) {               // x: 4M elems
      src = x + (size_t)c * 8;
      dst = xb + (size_t)c * 8;
    } else {
      const int cw = c - 524288;
      const int w = cw >> 17;       // 131072 chunks per weight
      const int off = (cw & 131071) * 8;
      const float* wp = (w == 0) ? wq : (w == 1) ? wk : (w == 2) ? wv : wo;
      src = wp + off;
      dst = Wb + (size_t)w * 1048576 + off;
    }
    f32x4 a = *(const f32x4*)src;
    f32x4 b = *(const f32x4*)(src + 4);
    bf16x8 r;
    r[0] = (bf16)a[0]; r[1] = (bf16)a[1]; r[2] = (bf16)a[2]; r[3] = (bf16)a[3];
    r[4] = (bf16)b[0]; r[5] = (bf16)b[1]; r[6] = (bf16)b[2]; r[7] = (bf16)b[3];
    *(bf16x8*)dst = r;
  }
}

// ---------------- m97-style 128x128 GEMM core (C = A * B^T, bf16) ----------
// XOR-swizzled LDS tiles (see async16 comment).
__device__ __forceinline__ void mm128_core(const bf16* __restrict__ A,
                                           const bf16* __restrict__ B,
                                           int K, int mbase, int nbase,
                                           bf16* As, bf16* Bs,
                                           f32x4 acc[4][4]) {
  const int tid  = threadIdx.x;
  const int lane = tid & 63;
  const int wave = tid >> 6;
  const int lrow = lane & 15;
  const int quad = lane >> 4;
  const int wr = (wave >> 1) * 64;
  const int wc = (wave & 1) * 64;
  const int srow = tid >> 3;               // staging row within 32-row group
  const int scol = (tid & 7) * 8;          // LDS staging col (elems)
  const int sx   = (((tid & 7) ^ (srow & 7))) * 8;  // swizzled global col

  for (int k0 = 0; k0 < K; k0 += 64) {
#pragma unroll
    for (int i = 0; i < 4; ++i) {
      async16(&As[(i * 32 + srow) * 64 + scol],
              &A[(size_t)(mbase + i * 32 + srow) * K + k0 + sx]);
      async16(&Bs[(i * 32 + srow) * 64 + scol],
              &B[(size_t)(nbase + i * 32 + srow) * K + k0 + sx]);
    }
    __syncthreads();
#pragma unroll
    for (int h = 0; h < 2; ++h) {
      const int cx = ((h * 4 + quad) ^ (lrow & 7)) * 8;   // swizzled read col
      bf16x8 af[4], bfr[4];
#pragma unroll
      for (int i = 0; i < 4; ++i) {
        af[i]  = *(const bf16x8*)&As[(wr + i * 16 + lrow) * 64 + cx];
        bfr[i] = *(const bf16x8*)&Bs[(wc + i * 16 + lrow) * 64 + cx];
      }
#pragma unroll
      for (int mt = 0; mt < 4; ++mt)
#pragma unroll
        for (int nt = 0; nt < 4; ++nt)
          acc[mt][nt] = __builtin_amdgcn_mfma_f32_16x16x32_bf16(af[mt], bfr[nt], acc[mt][nt], 0, 0, 0);
    }
    __syncthreads();
  }
}

// QKV fused: B = [wq;wk;wv] (3072 x 1024). 1-D grid with XCD-locality remap:
// XCD (lin&7) owns 3 fixed N-bands x all 32 M-tiles -> W band (768 KB) stays
// resident in that XCD's L2; x band reused 3x per visit.
// n<1024 -> Q, <2048 -> K, else V written TRANSPOSED into Vt.
__global__ __launch_bounds__(256) void qkv_gemm(const bf16* __restrict__ A,
                                                const bf16* __restrict__ B,
                                                bf16* __restrict__ Q,
                                                bf16* __restrict__ Kb,
                                                bf16* __restrict__ Vt) {
  __shared__ bf16 As[128 * 64];
  __shared__ bf16 Bs[128 * 64];
  const int lane = threadIdx.x & 63;
  const int wave = threadIdx.x >> 6;
  const int lrow = lane & 15;
  const int quad = lane >> 4;
  const int wr = (wave >> 1) * 64;
  const int wc = (wave & 1) * 64;
  const int lin = blockIdx.x;            // 0..767
  const int xcd = lin & 7;
  const int idx = lin >> 3;              // 0..95
  const int nbase = (xcd * 3 + idx % 3) * 128;   // 24 N-tiles, 3 per XCD
  const int mbase = (idx / 3) * 128;             // 32 M-tiles

  f32x4 acc[4][4] = {};
  mm128_core(A, B, DIN, mbase, nbase, As, Bs, acc);

#pragma unroll
  for (int mt = 0; mt < 4; ++mt) {
    const int m0 = mbase + wr + mt * 16 + quad * 4;
#pragma unroll
    for (int nt = 0; nt < 4; ++nt) {
      const int n16 = nbase + wc + nt * 16;   // 16-aligned; region uniform
      const int n = n16 + lrow;
      if (n16 < 1024) {
#pragma unroll
        for (int rr = 0; rr < 4; ++rr)
          Q[(size_t)(m0 + rr) * 1024 + n] = (bf16)acc[mt][nt][rr];
      } else if (n16 < 2048) {
#pragma unroll
        for (int rr = 0; rr < 4; ++rr)
          Kb[(size_t)(m0 + rr) * 1024 + (n - 1024)] = (bf16)acc[mt][nt][rr];
      } else {
        const int nn = n - 2048;
        const int row = ((m0 >> 11) * 16 + (nn >> 6)) * 64 + (nn & 63);
        bf16x4 ov;
#pragma unroll
        for (int rr = 0; rr < 4; ++rr) ov[rr] = (bf16)acc[mt][nt][rr];
        *(bf16x4*)&Vt[(size_t)row * SEQ + (m0 & 2047)] = ov;
      }
    }
  }
}

// ---------------- proj GEMM: tile 128x64 (2 blocks/CU), XCD remap ----------
__global__ __launch_bounds__(256) void proj_gemm(const bf16* __restrict__ A,
                                                 const bf16* __restrict__ B,
                                                 float* __restrict__ C) {
  __shared__ bf16 As[128 * 64];
  __shared__ bf16 Bs[64 * 64];
  const int tid  = threadIdx.x;
  const int lane = tid & 63;
  const int wave = tid >> 6;
  const int lrow = lane & 15;
  const int quad = lane >> 4;
  const int wr = (wave >> 1) * 64;
  const int wc = (wave & 1) * 32;
  const int lin = blockIdx.x;            // 0..511
  const int xcd = lin & 7;
  const int idx = lin >> 3;              // 0..63
  const int nbase = (xcd * 2 + (idx & 1)) * 64;  // 16 N-tiles, 2 per XCD
  const int mbase = (idx >> 1) * 128;            // 32 M-tiles
  const int srow = tid >> 3;
  const int scol = (tid & 7) * 8;
  const int sx   = ((tid & 7) ^ (srow & 7)) * 8;

  f32x4 acc[4][2] = {};

  for (int k0 = 0; k0 < DIMM; k0 += 64) {
#pragma unroll
    for (int i = 0; i < 4; ++i)
      async16(&As[(i * 32 + srow) * 64 + scol],
              &A[(size_t)(mbase + i * 32 + srow) * DIMM + k0 + sx]);
#pragma unroll
    for (int i = 0; i < 2; ++i)
      async16(&Bs[(i * 32 + srow) * 64 + scol],
              &B[(size_t)(nbase + i * 32 + srow) * DIMM + k0 + sx]);
    __syncthreads();
#pragma unroll
    for (int h = 0; h < 2; ++h) {
      const int cx = ((h * 4 + quad) ^ (lrow & 7)) * 8;
      bf16x8 af[4], bfr[2];
#pragma unroll
      for (int i = 0; i < 4; ++i)
        af[i] = *(const bf16x8*)&As[(wr + i * 16 + lrow) * 64 + cx];
#pragma unroll
      for (int i = 0; i < 2; ++i)
        bfr[i] = *(const bf16x8*)&Bs[(wc + i * 16 + lrow) * 64 + cx];
#pragma unroll
      for (int mt = 0; mt < 4; ++mt)
#pragma unroll
        for (int nt = 0; nt < 2; ++nt)
          acc[mt][nt] = __builtin_amdgcn_mfma_f32_16x16x32_bf16(af[mt], bfr[nt], acc[mt][nt], 0, 0, 0);
    }
    __syncthreads();
  }

#pragma unroll
  for (int mt = 0; mt < 4; ++mt) {
    const int m0 = mbase + wr + mt * 16 + quad * 4;
#pragma unroll
    for (int nt = 0; nt < 2; ++nt) {
      const int n = nbase + wc + nt * 16 + lrow;
#pragma unroll
      for (int rr = 0; rr < 4; ++rr)
        C[(size_t)(m0 + rr) * 1024 + n] = acc[mt][nt][rr];
    }
  }
}

// ---------------- Causal flash attention (R9-proven, 512 thr) --------------
// Block = 8 waves = 128 q-rows of one (b,h). K/Vt tiles staged to double-
// buffered XOR-swizzled LDS via global_load_lds; conflict-free ds_read_b128.
__global__ __launch_bounds__(512, 4) void attn(const bf16* __restrict__ Q,
                                               const bf16* __restrict__ K,
                                               const bf16* __restrict__ Vt,
                                               bf16* __restrict__ O) {
  __shared__ bf16 Ks[2][64 * 64];
  __shared__ bf16 Vts[2][64 * 64];
  __shared__ bf16 Plds[8][16 * LDP];
  const int tid  = threadIdx.x;
  const int wave = tid >> 6;
  const int lane = tid & 63;
  const int lrow = lane & 15;
  const int quad = lane >> 4;
  const int bh = blockIdx.x & 31;        // same-bh -> same XCD residue
  const int g  = blockIdx.x >> 5;        // 0..15
  const int qc = (g < 8) ? g : 23 - g;   // paired: CU's 2 blocks sum 34 tiles
  const int b  = bh >> 4;
  const int h  = bh & 15;
  const int qw = qc * 128 + wave * 16;   // this wave's q-tile base
  const int ntiles = 2 * qc + 2;

  const bf16* Qh  = Q  + (size_t)(b * SEQ) * DIMM + h * HD;
  const bf16* Kh  = K  + (size_t)(b * SEQ) * DIMM + h * HD;
  const bf16* Vth = Vt + (size_t)bh * 64 * SEQ;
  bf16* Pw = Plds[wave];

  // staging coords: 512 thr cover 64 rows x 128B; swizzled global col
  const int srow = tid >> 3;             // 0..63
  const int scol = (tid & 7) * 8;        // LDS col (elems)
  const int sx   = ((tid & 7) ^ (srow & 7)) * 8;  // global col (swizzle)
  const int cx0 = ((0 + quad) ^ (lrow & 7)) * 8;
  const int cx1 = ((4 + quad) ^ (lrow & 7)) * 8;

  bf16x8 qf0 = *(const bf16x8*)&Qh[(size_t)(qw + lrow) * DIMM + quad * 8];
  bf16x8 qf1 = *(const bf16x8*)&Qh[(size_t)(qw + lrow) * DIMM + 32 + quad * 8];

  // prologue: stage tile 0 into buf 0
  async16(&Ks[0][srow * 64 + scol],  &Kh[(size_t)srow * DIMM + sx]);
  async16(&Vts[0][srow * 64 + scol], &Vth[(size_t)srow * SEQ + sx]);
  __syncthreads();

  float m_i = -1e30f, l_i = 0.f;
  f32x4 o_acc[4] = {};
  int cur = 0;

  for (int kt = 0; kt < ntiles; ++kt) {
    const int kbase = kt * 64;
    // issue next tile's staging into the other buffer (completes at barrier)
    if (kt + 1 < ntiles) {
      const int nb = kbase + 64;
      async16(&Ks[cur ^ 1][srow * 64 + scol],  &Kh[(size_t)(nb + srow) * DIMM + sx]);
      async16(&Vts[cur ^ 1][srow * 64 + scol], &Vth[(size_t)srow * SEQ + nb + sx]);
    }
    if (kbase <= qw + 15) {   // wave-uniform causal participation
      const bf16* Kc = Ks[cur];
      const bf16* Vc = Vts[cur];
      // ---- S^T = K Q^T from LDS ----
      f32x4 s[4] = {};
#pragma unroll
      for (int gg = 0; gg < 4; ++gg) {
        bf16x8 kf0 = *(const bf16x8*)&Kc[(gg * 16 + lrow) * 64 + cx0];
        bf16x8 kf1 = *(const bf16x8*)&Kc[(gg * 16 + lrow) * 64 + cx1];
        s[gg] = __builtin_amdgcn_mfma_f32_16x16x32_bf16(kf0, qf0, s[gg], 0, 0, 0);
        s[gg] = __builtin_amdgcn_mfma_f32_16x16x32_bf16(kf1, qf1, s[gg], 0, 0, 0);
      }
      // ---- causal mask: boundary tiles only ----
      if (kbase + 63 > qw) {
        const int qrow = qw + lrow;
#pragma unroll
        for (int gg = 0; gg < 4; ++gg)
#pragma unroll
          for (int r = 0; r < 4; ++r)
            s[gg][r] = (kbase + gg * 16 + quad * 4 + r > qrow) ? -1e30f : s[gg][r];
      }
      // ---- online softmax over k: in-lane + 2 shfl ----
      float pm = s[0][0];
#pragma unroll
      for (int gg = 0; gg < 4; ++gg)
#pragma unroll
        for (int r = 0; r < 4; ++r) pm = fmaxf(pm, s[gg][r]);
      pm = fmaxf(pm, __shfl_xor(pm, 16));
      pm = fmaxf(pm, __shfl_xor(pm, 32));
      const float mn = fmaxf(m_i, pm);
      const float al = __expf((m_i - mn) * SCALE);
      float sum = 0.f;
#pragma unroll
      for (int gg = 0; gg < 4; ++gg) {
        bf16x4 pk;
#pragma unroll
        for (int r = 0; r < 4; ++r) {
          const float p = __expf((s[gg][r] - mn) * SCALE);
          sum += p;
          pk[r] = (bf16)p;
        }
        *(bf16x4*)&Pw[lrow * LDP + gg * 16 + quad * 4] = pk;
      }
      sum += __shfl_xor(sum, 16);
      sum += __shfl_xor(sum, 32);
      l_i = l_i * al + sum;
      m_i = mn;
#pragma unroll
      for (int dt = 0; dt < 4; ++dt)
#pragma unroll
        for (int r = 0; r < 4; ++r)
          o_acc[dt][r] *= al;
      // ---- vf loads between P write and read (covers LDS turnaround) ----
      bf16x8 vf[8];
#pragma unroll
      for (int dt = 0; dt < 4; ++dt) {
        vf[2 * dt]     = *(const bf16x8*)&Vc[(dt * 16 + lrow) * 64 + cx0];
        vf[2 * dt + 1] = *(const bf16x8*)&Vc[(dt * 16 + lrow) * 64 + cx1];
      }
      bf16x8 pf0 = *(const bf16x8*)&Pw[lrow * LDP + quad * 8];
      bf16x8 pf1 = *(const bf16x8*)&Pw[lrow * LDP + 32 + quad * 8];
      // ---- O^T += Vt P^T ----
#pragma unroll
      for (int dt = 0; dt < 4; ++dt) {
        o_acc[dt] = __builtin_amdgcn_mfma_f32_16x16x32_bf16(vf[2 * dt],     pf0, o_acc[dt], 0, 0, 0);
        o_acc[dt] = __builtin_amdgcn_mfma_f32_16x16x32_bf16(vf[2 * dt + 1], pf1, o_acc[dt], 0, 0, 0);
      }
    }
    __syncthreads();   // drains async staging; protects buffer swap
    cur ^= 1;
  }

  // ---- epilogue ----
  const float rl = __builtin_amdgcn_rcpf(l_i);
  bf16* Ob = O + (size_t)(b * SEQ + qw + lrow) * DIMM + h * HD;
#pragma unroll
  for (int dt = 0; dt < 4; ++dt) {
    bf16x4 ov;
#pragma unroll
    for (int r = 0; r < 4; ++r)
      ov[r] = (bf16)(o_acc[dt][r] * rl);
    *(bf16x4*)&Ob[dt * 16 + quad * 4] = ov;
  }
}

// ---------------- launch ----------------
extern "C" void kernel_launch(void* const* d_in, const int* in_sizes, int n_in,
                              void* d_out, int out_size, void* d_ws, size_t ws_size,
                              hipStream_t stream) {
  const float* x  = (const float*)d_in[0];
  const float* wq = (const float*)d_in[1];
  const float* wk = (const float*)d_in[2];
  const float* wv = (const float*)d_in[3];
  const float* wo = (const float*)d_in[4];

  const size_t M4 = (size_t)MTOT * DIMM;  // 4M elems
  bf16* xb  = (bf16*)d_ws;                // 4M   (reused as CTX after qkv)
  bf16* Wb  = xb + M4;                    // 4M: [wq|wk|wv|wo]
  bf16* Q   = Wb + M4;                    // 4M
  bf16* Kb  = Q + M4;                     // 4M
  bf16* Vt  = Kb + M4;                    // 4M
  bf16* CTX = xb;                         // alias: xb dead after qkv_gemm
  float* out = (float*)d_out;

  convert_all<<<dim3(1024), dim3(256), 0, stream>>>(x, wq, wk, wv, wo, xb, Wb);
  qkv_gemm<<<dim3(768), dim3(256), 0, stream>>>(xb, Wb, Q, Kb, Vt);
  attn<<<dim3(BATCH * NH * (SEQ / 128)), dim3(512), 0, stream>>>(Q, Kb, Vt, CTX);
  proj_gemm<<<dim3(512), dim3(256), 0, stream>>>(CTX, Wb + 3 * 1048576, out);
}